// Round 7
// baseline (406.450 us; speedup 1.0000x reference)
//
#include <hip/hip_runtime.h>
#include <float.h>

#define EPSV 1e-5f
#define DGRID 21
#define DPROD (21 * 21 * 21)

typedef __attribute__((ext_vector_type(8))) short bf16x8;
typedef __attribute__((ext_vector_type(4))) float f32x4;

// fp32 -> bf16 (RNE), bit pattern in short
__device__ __forceinline__ short f2bf(float x) {
    unsigned u = __float_as_uint(x);
    unsigned r = (u + 0x7FFFu + ((u >> 16) & 1u)) >> 16;
    return (short)r;
}

// ---------- helpers ----------
__device__ __forceinline__ int batch_of(int i, const int* __restrict__ offset, int B) {
    int b = 0;
    while (b < B - 1 && i >= offset[b]) ++b;
    return b;
}

// ---------- init: startEnc only (must complete before k_start's atomicMin) ----------
__global__ void k_init(int* startEnc, int B) {
    int tid = threadIdx.x;
    if (tid < B * 3) startEnc[tid] = 0x7FFFFFFF;              // +inf for non-neg floats
}

// ---------- per-batch coord min (segment_min) + counts zeroing ----------
__global__ void k_start(const float* __restrict__ coord, const int* __restrict__ offset,
                        int* startEnc, int* counts, int KSM, int N, int B) {
    // fold counts zeroing in (consumed by the NEXT kernel; no intra-launch ordering needed)
    int gtid = blockIdx.x * blockDim.x + threadIdx.x;
    for (int k = gtid; k < KSM; k += gridDim.x * blockDim.x) counts[k] = 0;

    __shared__ int smin[24];
    int t = threadIdx.x;
    if (t < B * 3) smin[t] = 0x7FFFFFFF;
    __syncthreads();
    int base = gtid * 4;
    int curb = -1;
    int m0 = 0x7FFFFFFF, m1 = 0x7FFFFFFF, m2 = 0x7FFFFFFF;
    for (int r = 0; r < 4; ++r) {
        int i = base + r;
        if (i >= N) break;
        int b = batch_of(i, offset, B);
        if (b != curb) {
            if (curb >= 0) {
                atomicMin(&smin[curb * 3 + 0], m0);
                atomicMin(&smin[curb * 3 + 1], m1);
                atomicMin(&smin[curb * 3 + 2], m2);
            }
            curb = b; m0 = m1 = m2 = 0x7FFFFFFF;
        }
        m0 = min(m0, __float_as_int(coord[(size_t)i * 3 + 0]));
        m1 = min(m1, __float_as_int(coord[(size_t)i * 3 + 1]));
        m2 = min(m2, __float_as_int(coord[(size_t)i * 3 + 2]));
    }
    if (curb >= 0) {
        atomicMin(&smin[curb * 3 + 0], m0);
        atomicMin(&smin[curb * 3 + 1], m1);
        atomicMin(&smin[curb * 3 + 2], m2);
    }
    __syncthreads();
    if (t < B * 3 && smin[t] != 0x7FFFFFFF) atomicMin(&startEnc[t], smin[t]);
}

// ---------- per-point voxel key + histogram (fixed conservative D=21: order-preserving) ----------
__global__ void k_count(const float* __restrict__ coord, const int* __restrict__ offset,
                        const int* __restrict__ startEnc, const float* __restrict__ gsP,
                        int* counts, int* vkey, int N, int B) {
    int i = blockIdx.x * blockDim.x + threadIdx.x;
    if (i >= N) return;
    float inv_gs = 1.0f / gsP[0];
    int b = batch_of(i, offset, B);
    float s0 = __int_as_float(startEnc[b * 3 + 0]);
    float s1 = __int_as_float(startEnc[b * 3 + 1]);
    float s2 = __int_as_float(startEnc[b * 3 + 2]);
    int vx = min(DGRID - 1, (int)floorf((coord[(size_t)i * 3 + 0] - s0) * inv_gs));
    int vy = min(DGRID - 1, (int)floorf((coord[(size_t)i * 3 + 1] - s1) * inv_gs));
    int vz = min(DGRID - 1, (int)floorf((coord[(size_t)i * 3 + 2] - s2) * inv_gs));
    int k = ((b * DGRID + vx) * DGRID + vy) * DGRID + vz;
    vkey[i] = k;
    atomicAdd(&counts[k], 1);
}

// ---------- scan pass 1: per-chunk (1024 keys) totals ----------
__global__ void k_scan1(const int* __restrict__ counts, int* occPart, int* cntPart, int KSM) {
    __shared__ int so[256], sc[256];
    int t = threadIdx.x;
    int base = blockIdx.x * 1024 + t * 4;
    int o = 0, c = 0;
    for (int r = 0; r < 4; ++r) {
        int k = base + r;
        if (k < KSM) { int cnt = counts[k]; o += (cnt > 0); c += cnt; }
    }
    so[t] = o; sc[t] = c;
    __syncthreads();
    for (int s = 128; s > 0; s >>= 1) {
        if (t < s) { so[t] += so[t + s]; sc[t] += sc[t + s]; }
        __syncthreads();
    }
    if (t == 0) { occPart[blockIdx.x] = so[0]; cntPart[blockIdx.x] = sc[0]; }
}

// ---------- scan pass 2: exclusive scan of block partials ----------
__global__ void k_scan2(const int* occPart, const int* cntPart,
                        int* occPartEx, int* cntPartEx, int NBLK) {
    __shared__ int so[128], sc[128];
    int t = threadIdx.x;
    int o = (t < NBLK) ? occPart[t] : 0;
    int c = (t < NBLK) ? cntPart[t] : 0;
    so[t] = o; sc[t] = c;
    __syncthreads();
    for (int s = 1; s < 128; s <<= 1) {
        int ao = 0, ac = 0;
        if (t >= s) { ao = so[t - s]; ac = sc[t - s]; }
        __syncthreads();
        so[t] += ao; sc[t] += ac;
        __syncthreads();
    }
    if (t < NBLK) { occPartEx[t] = so[t] - o; cntPartEx[t] = sc[t] - c; }
}

// ---------- scan pass 3: full exclusive scans + cluster-indexed counts/starts ----------
__global__ void k_scan3(const int* __restrict__ counts, const int* occPartEx, const int* cntPartEx,
                        int* occScan, int* cntScan, int* cursor, int* cntC, int* cstartC, int KSM) {
    __shared__ int so[256], sc[256];
    int t = threadIdx.x;
    int base = blockIdx.x * 1024 + t * 4;
    int o[4], c[4];
    int tO = 0, tC = 0;
    for (int r = 0; r < 4; ++r) {
        int k = base + r;
        int cnt = (k < KSM) ? counts[k] : 0;
        o[r] = (cnt > 0); c[r] = cnt;
        tO += o[r]; tC += c[r];
    }
    so[t] = tO; sc[t] = tC;
    __syncthreads();
    for (int s = 1; s < 256; s <<= 1) {
        int ao = 0, ac = 0;
        if (t >= s) { ao = so[t - s]; ac = sc[t - s]; }
        __syncthreads();
        so[t] += ao; sc[t] += ac;
        __syncthreads();
    }
    int exO = so[t] - tO + occPartEx[blockIdx.x];
    int exC = sc[t] - tC + cntPartEx[blockIdx.x];
    for (int r = 0; r < 4; ++r) {
        int k = base + r;
        if (k < KSM) {
            occScan[k] = exO; cntScan[k] = exC; cursor[k] = 0;
            if (c[r] > 0) { cntC[exO] = c[r]; cstartC[exO] = exC; }
            exO += o[r]; exC += c[r];
        }
    }
}

// ---------- scatter: bucket point lists + inverse (no coord atomics) ----------
__global__ void k_scatter(const int* __restrict__ vkey,
                          const int* __restrict__ occScan, const int* __restrict__ cntScan,
                          int* cursor, int* plist, float* __restrict__ dout,
                          int N, int B, int M) {
    int i = blockIdx.x * blockDim.x + threadIdx.x;
    if (i >= N) return;
    int k = vkey[i];
    int cidx = occScan[k];
    int pos = cntScan[k] + atomicAdd(&cursor[k], 1);
    plist[pos] = i;
    dout[(size_t)67 * M + B + i] = (float)cidx;               // inverse
}

// ---------- fused MLP + segment-max via MFMA: 4 waves/block, one cluster per wave ----------
// A-frag: 16 gathered cluster points (lane m=lane&15, k=quad*8+j), vector loads.
// B-frags: W columns (n=t*16+col, k=quad*8+j), loaded once into registers.
// C/D layout: col=lane&15, row=quad*4+reg. Max over rows via shfl_xor(16/32).
// Pad rows replicate a real point (max-safe); stats masked by row<cnt.
// Coord mean: lanes 0-15 gather coord[p], xor-shuffle reduce, lane 0 writes.
// 256-thr blocks lift the 16-workgroup/CU slot cap (64-thr blocks -> 52% occ).
__launch_bounds__(256)
__global__ void k_pool(const float* __restrict__ feat, const float* __restrict__ coord,
                       const float* __restrict__ W,
                       const int* __restrict__ cstartC, const int* __restrict__ cntC,
                       const int* __restrict__ plist,
                       float* __restrict__ dout, float* __restrict__ statPart, int M) {
    const int lane = threadIdx.x & 63;
    const int wid  = threadIdx.x >> 6;
    const int gw = blockIdx.x * 4 + wid;
    const int nw = gridDim.x * 4;
    const int col  = lane & 15;
    const int quad = lane >> 4;

    bf16x8 Bf[4];
#pragma unroll
    for (int t = 0; t < 4; ++t) {
#pragma unroll
        for (int j = 0; j < 8; ++j) {
            int k = quad * 8 + j;
            Bf[t][j] = f2bf(W[k * 64 + t * 16 + col]);
        }
    }

    float sumA[4] = {0.f, 0.f, 0.f, 0.f};
    float sqA[4]  = {0.f, 0.f, 0.f, 0.f};

    for (int cid = gw; cid < M; cid += nw) {
        int ps  = cstartC[cid];                 // wave-uniform (same-addr vector load)
        int cnt = cntC[cid];
        float maxA[4] = {-FLT_MAX, -FLT_MAX, -FLT_MAX, -FLT_MAX};
        float cx = 0.f, cy = 0.f, cz = 0.f;

        for (int base = 0; base < cnt; base += 16) {
            int m = base + col;
            int idx = min(m, cnt - 1);
            int p = plist[ps + idx];            // per-lane gather (64B window)
            const float4* rowp = reinterpret_cast<const float4*>(feat + (size_t)p * 32 + quad * 8);
            float4 a0 = rowp[0];
            float4 a1 = rowp[1];
            if (lane < 16 && m < cnt) {         // coord accumulation, quad-0 lanes only
                cx += coord[(size_t)p * 3 + 0];
                cy += coord[(size_t)p * 3 + 1];
                cz += coord[(size_t)p * 3 + 2];
            }
            bf16x8 Af;
            Af[0] = f2bf(a0.x); Af[1] = f2bf(a0.y); Af[2] = f2bf(a0.z); Af[3] = f2bf(a0.w);
            Af[4] = f2bf(a1.x); Af[5] = f2bf(a1.y); Af[6] = f2bf(a1.z); Af[7] = f2bf(a1.w);
            f32x4 Cz = {0.f, 0.f, 0.f, 0.f};
#pragma unroll
            for (int t = 0; t < 4; ++t) {
                f32x4 Cv = __builtin_amdgcn_mfma_f32_16x16x32_bf16(Af, Bf[t], Cz, 0, 0, 0);
#pragma unroll
                for (int r = 0; r < 4; ++r) {
                    int rowPt = base + quad * 4 + r;
                    bool valid = rowPt < cnt;
                    float v = Cv[r];
                    maxA[t] = fmaxf(maxA[t], valid ? v : -FLT_MAX);
                    sumA[t] += valid ? v : 0.f;
                    sqA[t]  += valid ? v * v : 0.f;
                }
            }
        }
        float outv = 0.f;
#pragma unroll
        for (int t = 0; t < 4; ++t) {
            float v = maxA[t];
            v = fmaxf(v, __shfl_xor(v, 16, 64));
            v = fmaxf(v, __shfl_xor(v, 32, 64));
            if (quad == t) outv = v;            // channel quad*16+col == lane
        }
        dout[(size_t)3 * M + (size_t)cid * 64 + lane] = outv;   // raw max; BN later

        // coord mean: reduce lanes 0-15, lane 0 writes
        cx += __shfl_xor(cx, 1, 64); cx += __shfl_xor(cx, 2, 64);
        cx += __shfl_xor(cx, 4, 64); cx += __shfl_xor(cx, 8, 64);
        cy += __shfl_xor(cy, 1, 64); cy += __shfl_xor(cy, 2, 64);
        cy += __shfl_xor(cy, 4, 64); cy += __shfl_xor(cy, 8, 64);
        cz += __shfl_xor(cz, 1, 64); cz += __shfl_xor(cz, 2, 64);
        cz += __shfl_xor(cz, 4, 64); cz += __shfl_xor(cz, 8, 64);
        if (lane == 0) {
            float inv = 1.0f / (float)cnt;
            dout[(size_t)cid * 3 + 0] = cx * inv;
            dout[(size_t)cid * 3 + 1] = cy * inv;
            dout[(size_t)cid * 3 + 2] = cz * inv;
        }
    }

    float so = 0.f, qo = 0.f;
#pragma unroll
    for (int t = 0; t < 4; ++t) {
        float s = sumA[t];
        s += __shfl_xor(s, 16, 64);
        s += __shfl_xor(s, 32, 64);
        float q = sqA[t];
        q += __shfl_xor(q, 16, 64);
        q += __shfl_xor(q, 32, 64);
        if (quad == t) { so = s; qo = q; }
    }
    statPart[(size_t)gw * 128 + lane] = so;
    statPart[(size_t)gw * 128 + 64 + lane] = qo;
}

// ---------- reduce stat partials -> BN params (one block per channel) ----------
__global__ void k_statred(const float* __restrict__ statPart,
                          const float* __restrict__ gamma, const float* __restrict__ beta,
                          float* bnA, float* bnB, int NB, int N) {
    __shared__ float s1[256], s2[256];
    int c = blockIdx.x;
    int t = threadIdx.x;
    float a = 0.f, b = 0.f;
    for (int bb = t; bb < NB; bb += 256) {
        a += statPart[(size_t)bb * 128 + c];
        b += statPart[(size_t)bb * 128 + 64 + c];
    }
    s1[t] = a; s2[t] = b;
    __syncthreads();
    for (int s = 128; s > 0; s >>= 1) {
        if (t < s) { s1[t] += s1[t + s]; s2[t] += s2[t + s]; }
        __syncthreads();
    }
    if (t == 0) {
        float invN = 1.0f / (float)N;
        float mean = s1[0] * invN;
        float var = s2[0] * invN - mean * mean;
        float aa = gamma[c] / sqrtf(var + EPSV);
        bnA[c] = aa;
        bnB[c] = beta[c] - mean * aa;
    }
}

// ---------- finalize: BN+ReLU on maxima, offset_out ----------
__global__ void k_final(float* __restrict__ dout, const float* __restrict__ bnA,
                        const float* __restrict__ bnB,
                        const int* __restrict__ occScan, int M, int B) {
    size_t stride = (size_t)gridDim.x * blockDim.x;
    size_t tid0 = (size_t)blockIdx.x * blockDim.x + threadIdx.x;
    size_t totF = (size_t)M * 64;
    for (size_t t = tid0; t < totF; t += stride) {
        int c = (int)(t & 63);
        float v = dout[(size_t)3 * M + t];
        dout[(size_t)3 * M + t] = fmaxf(bnA[c] * v + bnB[c], 0.f);
    }
    if (tid0 < (size_t)B) {
        int val = (tid0 == (size_t)(B - 1)) ? M : occScan[(int)(tid0 + 1) * DPROD];
        dout[(size_t)67 * M + tid0] = (float)val;
    }
}

extern "C" void kernel_launch(void* const* d_in, const int* in_sizes, int n_in,
                              void* d_out, int out_size, void* d_ws, size_t ws_size,
                              hipStream_t stream) {
    const float* coord = (const float*)d_in[0];
    const float* feat  = (const float*)d_in[1];
    const int*   offset = (const int*)d_in[2];
    const float* W     = (const float*)d_in[3];
    const float* gamma = (const float*)d_in[4];
    const float* beta  = (const float*)d_in[5];
    const float* gsP   = (const float*)d_in[6];
    float* dout = (float*)d_out;

    const int N = in_sizes[0] / 3;
    const int B = in_sizes[2];
    const int M = (out_size - B - N) / 67;         // dout layout fixes M
    const int KSM = B * DPROD;                     // conservative keyspace, order-preserving
    const int NBLK = (KSM + 1023) / 1024;          // scan chunks (<=128)
    const int NBPL = 2048;                         // k_pool blocks (4 waves each)
    const int NWPL = NBPL * 4;                     // wave partitions

    // workspace layout (int units)
    int* wsI = (int*)d_ws;
    int* startEnc  = wsI + 0;                // B*3
    float* bnA     = (float*)(wsI + 64);     // 64
    float* bnB     = (float*)(wsI + 128);    // 64
    int* occPart   = wsI + 256;              // 128
    int* cntPart   = wsI + 384;              // 128
    int* occPartEx = wsI + 512;              // 128
    int* cntPartEx = wsI + 640;              // 128
    int* counts    = wsI + 1024;             // KSM
    int* occScan   = counts + KSM;           // KSM
    int* cntScan   = occScan + KSM;          // KSM
    int* cursor    = cntScan + KSM;          // KSM
    int* cntC      = cursor + KSM;           // KSM (>= M)
    int* cstartC   = cntC + KSM;             // KSM (>= M)
    int* vkey      = cstartC + KSM;          // N
    int* plist     = vkey + N;               // N
    float* statPart = (float*)(plist + N);   // NWPL*128

    const int TPB = 256;
    int gChunk = (N + 1023) / 1024;
    int gPoint = (N + TPB - 1) / TPB;

    k_init<<<1, 64, 0, stream>>>(startEnc, B);
    k_start<<<gChunk, TPB, 0, stream>>>(coord, offset, startEnc, counts, KSM, N, B);
    k_count<<<gPoint, TPB, 0, stream>>>(coord, offset, startEnc, gsP, counts, vkey, N, B);
    k_scan1<<<NBLK, TPB, 0, stream>>>(counts, occPart, cntPart, KSM);
    k_scan2<<<1, 128, 0, stream>>>(occPart, cntPart, occPartEx, cntPartEx, NBLK);
    k_scan3<<<NBLK, TPB, 0, stream>>>(counts, occPartEx, cntPartEx, occScan, cntScan,
                                      cursor, cntC, cstartC, KSM);
    k_scatter<<<gPoint, TPB, 0, stream>>>(vkey, occScan, cntScan, cursor, plist,
                                          dout, N, B, M);
    k_pool<<<NBPL, TPB, 0, stream>>>(feat, coord, W, cstartC, cntC, plist, dout, statPart, M);
    k_statred<<<64, 256, 0, stream>>>(statPart, gamma, beta, bnA, bnB, NWPL, N);
    k_final<<<1024, TPB, 0, stream>>>(dout, bnA, bnB, occScan, M, B);
}

// Round 8
// 390.836 us; speedup vs baseline: 1.0400x; 1.0400x over previous
//
#include <hip/hip_runtime.h>
#include <float.h>

#define EPSV 1e-5f
#define DGRID 21
#define DPROD (21 * 21 * 21)

typedef __attribute__((ext_vector_type(8))) short bf16x8;
typedef __attribute__((ext_vector_type(4))) float f32x4;

// fp32 -> bf16 (RNE), bit pattern in short
__device__ __forceinline__ short f2bf(float x) {
    unsigned u = __float_as_uint(x);
    unsigned r = (u + 0x7FFFu + ((u >> 16) & 1u)) >> 16;
    return (short)r;
}

// ---------- helpers ----------
__device__ __forceinline__ int batch_of(int i, const int* __restrict__ offset, int B) {
    int b = 0;
    while (b < B - 1 && i >= offset[b]) ++b;
    return b;
}

// ---------- init: startEnc only (must complete before k_start's atomicMin) ----------
__global__ void k_init(int* startEnc, int B) {
    int tid = threadIdx.x;
    if (tid < B * 3) startEnc[tid] = 0x7FFFFFFF;              // +inf for non-neg floats
}

// ---------- per-batch coord min (segment_min) + counts zeroing ----------
__global__ void k_start(const float* __restrict__ coord, const int* __restrict__ offset,
                        int* startEnc, int* counts, int KSM, int N, int B) {
    int gtid = blockIdx.x * blockDim.x + threadIdx.x;
    for (int k = gtid; k < KSM; k += gridDim.x * blockDim.x) counts[k] = 0;

    __shared__ int smin[24];
    int t = threadIdx.x;
    if (t < B * 3) smin[t] = 0x7FFFFFFF;
    __syncthreads();
    int base = gtid * 4;
    int curb = -1;
    int m0 = 0x7FFFFFFF, m1 = 0x7FFFFFFF, m2 = 0x7FFFFFFF;
    for (int r = 0; r < 4; ++r) {
        int i = base + r;
        if (i >= N) break;
        int b = batch_of(i, offset, B);
        if (b != curb) {
            if (curb >= 0) {
                atomicMin(&smin[curb * 3 + 0], m0);
                atomicMin(&smin[curb * 3 + 1], m1);
                atomicMin(&smin[curb * 3 + 2], m2);
            }
            curb = b; m0 = m1 = m2 = 0x7FFFFFFF;
        }
        m0 = min(m0, __float_as_int(coord[(size_t)i * 3 + 0]));
        m1 = min(m1, __float_as_int(coord[(size_t)i * 3 + 1]));
        m2 = min(m2, __float_as_int(coord[(size_t)i * 3 + 2]));
    }
    if (curb >= 0) {
        atomicMin(&smin[curb * 3 + 0], m0);
        atomicMin(&smin[curb * 3 + 1], m1);
        atomicMin(&smin[curb * 3 + 2], m2);
    }
    __syncthreads();
    if (t < B * 3 && smin[t] != 0x7FFFFFFF) atomicMin(&startEnc[t], smin[t]);
}

// ---------- per-point voxel key + histogram (fixed conservative D=21: order-preserving) ----------
__global__ void k_count(const float* __restrict__ coord, const int* __restrict__ offset,
                        const int* __restrict__ startEnc, const float* __restrict__ gsP,
                        int* counts, int* vkey, int N, int B) {
    int i = blockIdx.x * blockDim.x + threadIdx.x;
    if (i >= N) return;
    float inv_gs = 1.0f / gsP[0];
    int b = batch_of(i, offset, B);
    float s0 = __int_as_float(startEnc[b * 3 + 0]);
    float s1 = __int_as_float(startEnc[b * 3 + 1]);
    float s2 = __int_as_float(startEnc[b * 3 + 2]);
    int vx = min(DGRID - 1, (int)floorf((coord[(size_t)i * 3 + 0] - s0) * inv_gs));
    int vy = min(DGRID - 1, (int)floorf((coord[(size_t)i * 3 + 1] - s1) * inv_gs));
    int vz = min(DGRID - 1, (int)floorf((coord[(size_t)i * 3 + 2] - s2) * inv_gs));
    int k = ((b * DGRID + vx) * DGRID + vy) * DGRID + vz;
    vkey[i] = k;
    atomicAdd(&counts[k], 1);
}

// ---------- scan pass 1: per-chunk (1024 keys) totals ----------
__global__ void k_scan1(const int* __restrict__ counts, int* occPart, int* cntPart, int KSM) {
    __shared__ int so[256], sc[256];
    int t = threadIdx.x;
    int base = blockIdx.x * 1024 + t * 4;
    int o = 0, c = 0;
    for (int r = 0; r < 4; ++r) {
        int k = base + r;
        if (k < KSM) { int cnt = counts[k]; o += (cnt > 0); c += cnt; }
    }
    so[t] = o; sc[t] = c;
    __syncthreads();
    for (int s = 128; s > 0; s >>= 1) {
        if (t < s) { so[t] += so[t + s]; sc[t] += sc[t + s]; }
        __syncthreads();
    }
    if (t == 0) { occPart[blockIdx.x] = so[0]; cntPart[blockIdx.x] = sc[0]; }
}

// ---------- scan pass 2: exclusive scan of block partials ----------
__global__ void k_scan2(const int* occPart, const int* cntPart,
                        int* occPartEx, int* cntPartEx, int NBLK) {
    __shared__ int so[128], sc[128];
    int t = threadIdx.x;
    int o = (t < NBLK) ? occPart[t] : 0;
    int c = (t < NBLK) ? cntPart[t] : 0;
    so[t] = o; sc[t] = c;
    __syncthreads();
    for (int s = 1; s < 128; s <<= 1) {
        int ao = 0, ac = 0;
        if (t >= s) { ao = so[t - s]; ac = sc[t - s]; }
        __syncthreads();
        so[t] += ao; sc[t] += ac;
        __syncthreads();
    }
    if (t < NBLK) { occPartEx[t] = so[t] - o; cntPartEx[t] = sc[t] - c; }
}

// ---------- scan pass 3: full exclusive scans + cluster-indexed counts/starts ----------
__global__ void k_scan3(const int* __restrict__ counts, const int* occPartEx, const int* cntPartEx,
                        int* occScan, int* cntScan, int* cursor, int* cntC, int* cstartC, int KSM) {
    __shared__ int so[256], sc[256];
    int t = threadIdx.x;
    int base = blockIdx.x * 1024 + t * 4;
    int o[4], c[4];
    int tO = 0, tC = 0;
    for (int r = 0; r < 4; ++r) {
        int k = base + r;
        int cnt = (k < KSM) ? counts[k] : 0;
        o[r] = (cnt > 0); c[r] = cnt;
        tO += o[r]; tC += c[r];
    }
    so[t] = tO; sc[t] = tC;
    __syncthreads();
    for (int s = 1; s < 256; s <<= 1) {
        int ao = 0, ac = 0;
        if (t >= s) { ao = so[t - s]; ac = sc[t - s]; }
        __syncthreads();
        so[t] += ao; sc[t] += ac;
        __syncthreads();
    }
    int exO = so[t] - tO + occPartEx[blockIdx.x];
    int exC = sc[t] - tC + cntPartEx[blockIdx.x];
    for (int r = 0; r < 4; ++r) {
        int k = base + r;
        if (k < KSM) {
            occScan[k] = exO; cntScan[k] = exC; cursor[k] = 0;
            if (c[r] > 0) { cntC[exO] = c[r]; cstartC[exO] = exC; }
            exO += o[r]; exC += c[r];
        }
    }
}

// ---------- scatter: bucket point lists + inverse ----------
__global__ void k_scatter(const int* __restrict__ vkey,
                          const int* __restrict__ occScan, const int* __restrict__ cntScan,
                          int* cursor, int* plist, float* __restrict__ dout,
                          int N, int B, int M) {
    int i = blockIdx.x * blockDim.x + threadIdx.x;
    if (i >= N) return;
    int k = vkey[i];
    int cidx = occScan[k];
    int pos = cntScan[k] + atomicAdd(&cursor[k], 1);
    plist[pos] = i;
    dout[(size_t)67 * M + B + i] = (float)cidx;               // inverse
}

// ---------- fused MLP + segment-max via MFMA: one wave/block, TWO clusters per iter ----------
// Two independent gather chains in flight (plist latency of one overlaps feat
// loads of the other). Max needs NO masking (pad rows replicate a real point);
// stats masked by row<cnt (and by has2 for the duplicated second cluster).
// Coord mean: quads 1..3 gather components 0..2, reduce within quad, col-0 writes.
__launch_bounds__(64)
__global__ void k_pool(const float* __restrict__ feat, const float* __restrict__ coord,
                       const float* __restrict__ W,
                       const int* __restrict__ cstartC, const int* __restrict__ cntC,
                       const int* __restrict__ plist,
                       float* __restrict__ dout, float* __restrict__ statPart, int M) {
    const int lane = threadIdx.x;
    const int col  = lane & 15;
    const int quad = lane >> 4;
    const int nw = gridDim.x;
    const int gw = blockIdx.x;

    bf16x8 Bf[4];
#pragma unroll
    for (int t = 0; t < 4; ++t) {
#pragma unroll
        for (int j = 0; j < 8; ++j) {
            int k = quad * 8 + j;
            Bf[t][j] = f2bf(W[k * 64 + t * 16 + col]);
        }
    }

    float sumA[4] = {0.f, 0.f, 0.f, 0.f};
    float sqA[4]  = {0.f, 0.f, 0.f, 0.f};

    for (int c0 = gw; c0 < M; c0 += 2 * nw) {
        int c1 = c0 + nw;
        bool has2 = c1 < M;
        if (!has2) c1 = c0;
        int ps0 = cstartC[c0], n0 = cntC[c0];       // uniform -> s_load
        int ps1 = cstartC[c1], n1 = cntC[c1];
        int nmax = max(n0, n1);

        float maxA0[4] = {-FLT_MAX, -FLT_MAX, -FLT_MAX, -FLT_MAX};
        float maxA1[4] = {-FLT_MAX, -FLT_MAX, -FLT_MAX, -FLT_MAX};
        float cacc0 = 0.f, cacc1 = 0.f;             // coord component quad-1 (quads 1..3)

        for (int base = 0; base < nmax; base += 16) {
            int m = base + col;
            int idx0 = min(m, n0 - 1);
            int idx1 = min(m, n1 - 1);
            int p0 = plist[ps0 + idx0];             // two independent gather chains
            int p1 = plist[ps1 + idx1];
            const float4* r0p = reinterpret_cast<const float4*>(feat + (size_t)p0 * 32 + quad * 8);
            const float4* r1p = reinterpret_cast<const float4*>(feat + (size_t)p1 * 32 + quad * 8);
            float4 a00 = r0p[0], a01 = r0p[1];
            float4 a10 = r1p[0], a11 = r1p[1];
            if (quad > 0) {                         // coord: quads 1..3 load comp quad-1
                float v0 = coord[(size_t)p0 * 3 + (quad - 1)];
                float v1 = coord[(size_t)p1 * 3 + (quad - 1)];
                cacc0 += (m < n0) ? v0 : 0.f;
                cacc1 += (m < n1) ? v1 : 0.f;
            }
            bf16x8 Af0, Af1;
            Af0[0] = f2bf(a00.x); Af0[1] = f2bf(a00.y); Af0[2] = f2bf(a00.z); Af0[3] = f2bf(a00.w);
            Af0[4] = f2bf(a01.x); Af0[5] = f2bf(a01.y); Af0[6] = f2bf(a01.z); Af0[7] = f2bf(a01.w);
            Af1[0] = f2bf(a10.x); Af1[1] = f2bf(a10.y); Af1[2] = f2bf(a10.z); Af1[3] = f2bf(a10.w);
            Af1[4] = f2bf(a11.x); Af1[5] = f2bf(a11.y); Af1[6] = f2bf(a11.z); Af1[7] = f2bf(a11.w);
            f32x4 Cz = {0.f, 0.f, 0.f, 0.f};
#pragma unroll
            for (int t = 0; t < 4; ++t) {
                f32x4 v0 = __builtin_amdgcn_mfma_f32_16x16x32_bf16(Af0, Bf[t], Cz, 0, 0, 0);
                f32x4 v1 = __builtin_amdgcn_mfma_f32_16x16x32_bf16(Af1, Bf[t], Cz, 0, 0, 0);
#pragma unroll
                for (int r = 0; r < 4; ++r) {
                    int rowPt = base + quad * 4 + r;
                    maxA0[t] = fmaxf(maxA0[t], v0[r]);          // replication-safe, no mask
                    maxA1[t] = fmaxf(maxA1[t], v1[r]);
                    float m0 = (rowPt < n0) ? v0[r] : 0.f;
                    sumA[t] += m0; sqA[t] = fmaf(m0, m0, sqA[t]);
                    float m1 = (rowPt < n1 && has2) ? v1[r] : 0.f;
                    sumA[t] += m1; sqA[t] = fmaf(m1, m1, sqA[t]);
                }
            }
        }
        // per-channel max writes (duplicate write for !has2 is benign)
        float out0 = 0.f, out1 = 0.f;
#pragma unroll
        for (int t = 0; t < 4; ++t) {
            float v = maxA0[t];
            v = fmaxf(v, __shfl_xor(v, 16, 64));
            v = fmaxf(v, __shfl_xor(v, 32, 64));
            if (quad == t) out0 = v;
            float w = maxA1[t];
            w = fmaxf(w, __shfl_xor(w, 16, 64));
            w = fmaxf(w, __shfl_xor(w, 32, 64));
            if (quad == t) out1 = w;
        }
        dout[(size_t)3 * M + (size_t)c0 * 64 + lane] = out0;
        dout[(size_t)3 * M + (size_t)c1 * 64 + lane] = out1;

        // coord means: reduce within quad (cols), col-0 of quads 1..3 writes comp quad-1
        cacc0 += __shfl_xor(cacc0, 1, 64); cacc0 += __shfl_xor(cacc0, 2, 64);
        cacc0 += __shfl_xor(cacc0, 4, 64); cacc0 += __shfl_xor(cacc0, 8, 64);
        cacc1 += __shfl_xor(cacc1, 1, 64); cacc1 += __shfl_xor(cacc1, 2, 64);
        cacc1 += __shfl_xor(cacc1, 4, 64); cacc1 += __shfl_xor(cacc1, 8, 64);
        if (quad > 0 && col == 0) {
            dout[(size_t)c0 * 3 + (quad - 1)] = cacc0 / (float)n0;
            dout[(size_t)c1 * 3 + (quad - 1)] = cacc1 / (float)n1;
        }
    }

    float so = 0.f, qo = 0.f;
#pragma unroll
    for (int t = 0; t < 4; ++t) {
        float s = sumA[t];
        s += __shfl_xor(s, 16, 64);
        s += __shfl_xor(s, 32, 64);
        float q = sqA[t];
        q += __shfl_xor(q, 16, 64);
        q += __shfl_xor(q, 32, 64);
        if (quad == t) { so = s; qo = q; }
    }
    statPart[(size_t)gw * 128 + lane] = so;
    statPart[(size_t)gw * 128 + 64 + lane] = qo;
}

// ---------- reduce stat partials -> BN params (one block per channel) ----------
__global__ void k_statred(const float* __restrict__ statPart,
                          const float* __restrict__ gamma, const float* __restrict__ beta,
                          float* bnA, float* bnB, int NB, int N) {
    __shared__ float s1[256], s2[256];
    int c = blockIdx.x;
    int t = threadIdx.x;
    float a = 0.f, b = 0.f;
    for (int bb = t; bb < NB; bb += 256) {
        a += statPart[(size_t)bb * 128 + c];
        b += statPart[(size_t)bb * 128 + 64 + c];
    }
    s1[t] = a; s2[t] = b;
    __syncthreads();
    for (int s = 128; s > 0; s >>= 1) {
        if (t < s) { s1[t] += s1[t + s]; s2[t] += s2[t + s]; }
        __syncthreads();
    }
    if (t == 0) {
        float invN = 1.0f / (float)N;
        float mean = s1[0] * invN;
        float var = s2[0] * invN - mean * mean;
        float aa = gamma[c] / sqrtf(var + EPSV);
        bnA[c] = aa;
        bnB[c] = beta[c] - mean * aa;
    }
}

// ---------- finalize: BN+ReLU on maxima, offset_out ----------
__global__ void k_final(float* __restrict__ dout, const float* __restrict__ bnA,
                        const float* __restrict__ bnB,
                        const int* __restrict__ occScan, int M, int B) {
    size_t stride = (size_t)gridDim.x * blockDim.x;
    size_t tid0 = (size_t)blockIdx.x * blockDim.x + threadIdx.x;
    size_t totF = (size_t)M * 64;
    for (size_t t = tid0; t < totF; t += stride) {
        int c = (int)(t & 63);
        float v = dout[(size_t)3 * M + t];
        dout[(size_t)3 * M + t] = fmaxf(bnA[c] * v + bnB[c], 0.f);
    }
    if (tid0 < (size_t)B) {
        int val = (tid0 == (size_t)(B - 1)) ? M : occScan[(int)(tid0 + 1) * DPROD];
        dout[(size_t)67 * M + tid0] = (float)val;
    }
}

extern "C" void kernel_launch(void* const* d_in, const int* in_sizes, int n_in,
                              void* d_out, int out_size, void* d_ws, size_t ws_size,
                              hipStream_t stream) {
    const float* coord = (const float*)d_in[0];
    const float* feat  = (const float*)d_in[1];
    const int*   offset = (const int*)d_in[2];
    const float* W     = (const float*)d_in[3];
    const float* gamma = (const float*)d_in[4];
    const float* beta  = (const float*)d_in[5];
    const float* gsP   = (const float*)d_in[6];
    float* dout = (float*)d_out;

    const int N = in_sizes[0] / 3;
    const int B = in_sizes[2];
    const int M = (out_size - B - N) / 67;         // dout layout fixes M
    const int KSM = B * DPROD;                     // conservative keyspace, order-preserving
    const int NBLK = (KSM + 1023) / 1024;          // scan chunks (<=128)
    const int NBPL = 8192;                         // k_pool single-wave blocks

    // workspace layout (int units)
    int* wsI = (int*)d_ws;
    int* startEnc  = wsI + 0;                // B*3
    float* bnA     = (float*)(wsI + 64);     // 64
    float* bnB     = (float*)(wsI + 128);    // 64
    int* occPart   = wsI + 256;              // 128
    int* cntPart   = wsI + 384;              // 128
    int* occPartEx = wsI + 512;              // 128
    int* cntPartEx = wsI + 640;              // 128
    int* counts    = wsI + 1024;             // KSM
    int* occScan   = counts + KSM;           // KSM
    int* cntScan   = occScan + KSM;          // KSM
    int* cursor    = cntScan + KSM;          // KSM
    int* cntC      = cursor + KSM;           // KSM (>= M)
    int* cstartC   = cntC + KSM;             // KSM (>= M)
    int* vkey      = cstartC + KSM;          // N
    int* plist     = vkey + N;               // N
    float* statPart = (float*)(plist + N);   // NBPL*128

    const int TPB = 256;
    int gChunk = (N + 1023) / 1024;
    int gPoint = (N + TPB - 1) / TPB;

    k_init<<<1, 64, 0, stream>>>(startEnc, B);
    k_start<<<gChunk, TPB, 0, stream>>>(coord, offset, startEnc, counts, KSM, N, B);
    k_count<<<gPoint, TPB, 0, stream>>>(coord, offset, startEnc, gsP, counts, vkey, N, B);
    k_scan1<<<NBLK, TPB, 0, stream>>>(counts, occPart, cntPart, KSM);
    k_scan2<<<1, 128, 0, stream>>>(occPart, cntPart, occPartEx, cntPartEx, NBLK);
    k_scan3<<<NBLK, TPB, 0, stream>>>(counts, occPartEx, cntPartEx, occScan, cntScan,
                                      cursor, cntC, cstartC, KSM);
    k_scatter<<<gPoint, TPB, 0, stream>>>(vkey, occScan, cntScan, cursor, plist,
                                          dout, N, B, M);
    k_pool<<<NBPL, 64, 0, stream>>>(feat, coord, W, cstartC, cntC, plist, dout, statPart, M);
    k_statred<<<64, 256, 0, stream>>>(statPart, gamma, beta, bnA, bnB, NBPL, N);
    k_final<<<1024, TPB, 0, stream>>>(dout, bnA, bnB, occScan, M, B);
}